// Round 9
// baseline (228.035 us; speedup 1.0000x reference)
//
#include <hip/hip_runtime.h>

#define NPATH  2048
#define DIM    64
#define NSTEPS 500
#define PPW    16   // paths per wave-tile

typedef __attribute__((ext_vector_type(8))) short bf16x8;
typedef __attribute__((ext_vector_type(4))) float f32x4;

union FragU { bf16x8 v; unsigned int u[4]; };

__device__ __forceinline__ unsigned int pk_bf16(float lo, float hi) {
    unsigned int r;
    asm("v_cvt_pk_bf16_f32 %0, %1, %2" : "=v"(r) : "v"(lo), "v"(hi));
    return r;
}

// One wave per 16-path tile; the whole recurrence lives in registers.
// Transposed product: D[dim][path] = M' · X^T, M' row-permuted by
// sigma(beta, 4h+j) = 32*(beta>>1) + 8h + 4*(beta&1) + j, so the MFMA C-layout
// output (lane(c,h), reg j = dim sigma, path c) IS the B-fragment layout of
// the next step's X operand (lane(c,h) holds path c, k-dims {8h+e, 32+8h+e}).
// Recurrence closes via 8 in-register cvt_pk; no LDS/barriers in the loop.
// Matrix frags (16), biases, dW ring (depth 4) all in VGPRs; every global
// access is a contiguous float4 per lane (16B coalescing sweet spot).
__attribute__((amdgpu_waves_per_eu(1, 1)))
__global__ __launch_bounds__(64) void sde_reg_kernel(
    const float* __restrict__ x0,
    const float* __restrict__ dW,
    const float* __restrict__ drift,
    const float* __restrict__ drift_bias,
    const float* __restrict__ diffusion,
    const float* __restrict__ diffusion_bias,
    const float* __restrict__ ts,
    float* __restrict__ out)
{
    __shared__ float2 dtp[NSTEPS + 1];   // {dt, sqrt(dt)} per step

    const int lane = threadIdx.x;        // 0..63
    const int c    = lane & 15;          // path within tile / MFMA col
    const int h    = lane >> 4;          // k-slot group
    const int o8h  = 8 * h;
    const int p    = blockIdx.x * PPW + c;

    for (int i = lane; i < NSTEPS; i += 64) {
        const float d = ts[i + 1] - ts[i];          // f32-exact vs reference
        dtp[i] = make_float2(d, sqrtf(d));
    }
    if (lane == 0) dtp[NSTEPS] = make_float2(0.f, 0.f);

    static const int oo[4] = {0, 4, 32, 36};        // dim offset of block beta (rel. o8h)

    // ---- matrix A-fragments (row-permuted), built once -> 16 frags in VGPRs
    // A_beta[row=c][k=32kk+8h+e] = M[sigma(beta,c)][32kk+8h+e]
    FragU mf[2][4][2];                              // [mat][beta][kk]
#pragma unroll
    for (int mat = 0; mat < 2; ++mat) {
        const float* __restrict__ M = mat ? diffusion : drift;
#pragma unroll
        for (int b = 0; b < 4; ++b) {
            const int row = 32 * (b >> 1) + 8 * (c >> 2) + 4 * (b & 1) + (c & 3);
            const float* Mr = M + row * DIM + o8h;
#pragma unroll
            for (int kk = 0; kk < 2; ++kk) {
                const f32x4 lo = *(const f32x4*)(Mr + 32 * kk);
                const f32x4 hi = *(const f32x4*)(Mr + 32 * kk + 4);
                mf[mat][b][kk].u[0] = pk_bf16(lo[0], lo[1]);
                mf[mat][b][kk].u[1] = pk_bf16(lo[2], lo[3]);
                mf[mat][b][kk].u[2] = pk_bf16(hi[0], hi[1]);
                mf[mat][b][kk].u[3] = pk_bf16(hi[2], hi[3]);
            }
        }
    }

    // biases: acc-init vector for block beta = bias[o8h + oo[b] + j], j=0..3
    f32x4 bA[4], bC[4];
#pragma unroll
    for (int b = 0; b < 4; ++b) {
        bA[b] = *(const f32x4*)(drift_bias     + o8h + oo[b]);
        bC[b] = *(const f32x4*)(diffusion_bias + o8h + oo[b]);
    }

    // ---- state init: xs_[b][j] = x[path p][dim o8h+oo[b]+j] ----
    const float* pdw  = dW  + (size_t)p * NSTEPS * DIM + o8h;
    float*       pout = out + (size_t)p * (NSTEPS + 1) * DIM + o8h;
    f32x4 xs_[4];
#pragma unroll
    for (int b = 0; b < 4; ++b) {
        xs_[b] = *(const f32x4*)(x0 + p * DIM + o8h + oo[b]);
        __builtin_nontemporal_store(xs_[b], (f32x4*)(pout + oo[b]));  // ys[:,0,:]
    }

    // B-fragments of the state (k ascending within each 8-slot group)
    FragU xf0, xf1;
    xf0.u[0] = pk_bf16(xs_[0][0], xs_[0][1]); xf0.u[1] = pk_bf16(xs_[0][2], xs_[0][3]);
    xf0.u[2] = pk_bf16(xs_[1][0], xs_[1][1]); xf0.u[3] = pk_bf16(xs_[1][2], xs_[1][3]);
    xf1.u[0] = pk_bf16(xs_[2][0], xs_[2][1]); xf1.u[1] = pk_bf16(xs_[2][2], xs_[2][3]);
    xf1.u[2] = pk_bf16(xs_[3][0], xs_[3][1]); xf1.u[3] = pk_bf16(xs_[3][2], xs_[3][3]);

    // dW prefetch ring, depth 4 (f32x4 per block beta; all indices static)
    f32x4 Rs0[4], Rs1[4], Rs2[4], Rs3[4];
#pragma unroll
    for (int b = 0; b < 4; ++b) {
        Rs0[b] = *(const f32x4*)(pdw + 0 * DIM + oo[b]);
        Rs1[b] = *(const f32x4*)(pdw + 1 * DIM + oo[b]);
        Rs2[b] = *(const f32x4*)(pdw + 2 * DIM + oo[b]);
        Rs3[b] = *(const f32x4*)(pdw + 3 * DIM + oo[b]);
    }
    const float* pdwp = pdw + 4 * DIM;   // points at step s+4 for group s=0

    __syncthreads();                     // dtp ready (single wave, one-time)

    float2 dtc = dtp[0];

#define STEP(S, R, PF, KOFF)                                                  \
    {                                                                         \
        const float2 dtn = dtp[(S) + 1];                                      \
        f32x4 ad[4], ci[4];                                                   \
        _Pragma("unroll")                                                     \
        for (int b = 0; b < 4; ++b) {                                         \
            ad[b] = __builtin_amdgcn_mfma_f32_16x16x32_bf16(                  \
                        mf[0][b][0].v, xf0.v, bA[b], 0, 0, 0);                \
            ad[b] = __builtin_amdgcn_mfma_f32_16x16x32_bf16(                  \
                        mf[0][b][1].v, xf1.v, ad[b], 0, 0, 0);                \
            ci[b] = __builtin_amdgcn_mfma_f32_16x16x32_bf16(                  \
                        mf[1][b][0].v, xf0.v, bC[b], 0, 0, 0);                \
            ci[b] = __builtin_amdgcn_mfma_f32_16x16x32_bf16(                  \
                        mf[1][b][1].v, xf1.v, ci[b], 0, 0, 0);                \
        }                                                                     \
        _Pragma("unroll")                                                     \
        for (int b = 0; b < 4; ++b) {                                         \
            f32x4 xn;                                                         \
            _Pragma("unroll")                                                 \
            for (int j = 0; j < 4; ++j)                                       \
                xn[j] = fmaf(dtc.x, ad[b][j], xs_[b][j])                      \
                        + ci[b][j] * (dtc.y * R[b][j]);                       \
            xs_[b] = xn;                                                      \
            __builtin_nontemporal_store(                                      \
                xn, (f32x4*)(pout + (size_t)((S) + 1) * DIM + oo[b]));        \
        }                                                                     \
        xf0.u[0] = pk_bf16(xs_[0][0], xs_[0][1]);                             \
        xf0.u[1] = pk_bf16(xs_[0][2], xs_[0][3]);                             \
        xf0.u[2] = pk_bf16(xs_[1][0], xs_[1][1]);                             \
        xf0.u[3] = pk_bf16(xs_[1][2], xs_[1][3]);                             \
        xf1.u[0] = pk_bf16(xs_[2][0], xs_[2][1]);                             \
        xf1.u[1] = pk_bf16(xs_[2][2], xs_[2][3]);                             \
        xf1.u[2] = pk_bf16(xs_[3][0], xs_[3][1]);                             \
        xf1.u[3] = pk_bf16(xs_[3][2], xs_[3][3]);                             \
        if (PF) {                                                             \
            _Pragma("unroll")                                                 \
            for (int b = 0; b < 4; ++b)                                       \
                R[b] = *(const f32x4*)(pdwp + (KOFF) * DIM + oo[b]);          \
        }                                                                     \
        dtc = dtn;                                                            \
    }

    // main loop: 124 groups of 4 steps (0..495), group s prefetches s+4..s+7
    for (int it = 0; it < NSTEPS / 4 - 1; ++it) {
        const int s = it * 4;
        STEP(s + 0, Rs0, 1, 0)
        STEP(s + 1, Rs1, 1, 1)
        STEP(s + 2, Rs2, 1, 2)
        STEP(s + 3, Rs3, 1, 3)
        pdwp += 4 * DIM;
    }
    // epilogue: steps 496..499, no prefetch
    {
        const int s = NSTEPS - 4;
        STEP(s + 0, Rs0, 0, 0)
        STEP(s + 1, Rs1, 0, 1)
        STEP(s + 2, Rs2, 0, 2)
        STEP(s + 3, Rs3, 0, 3)
    }
#undef STEP
}

extern "C" void kernel_launch(void* const* d_in, const int* in_sizes, int n_in,
                              void* d_out, int out_size, void* d_ws, size_t ws_size,
                              hipStream_t stream) {
    const float* x0             = (const float*)d_in[0];
    const float* dW             = (const float*)d_in[1];
    const float* drift          = (const float*)d_in[2];
    const float* drift_bias     = (const float*)d_in[3];
    const float* diffusion      = (const float*)d_in[4];
    const float* diffusion_bias = (const float*)d_in[5];
    const float* ts             = (const float*)d_in[6];
    float* out = (float*)d_out;

    dim3 grid(NPATH / PPW);   // 128 blocks = 128 independent wave-tiles
    dim3 block(64);           // one wave
    hipLaunchKernelGGL(sde_reg_kernel, grid, block, 0, stream,
                       x0, dW, drift, drift_bias, diffusion, diffusion_bias,
                       ts, out);
}